// Round 4
// baseline (135.029 us; speedup 1.0000x reference)
//
#include <hip/hip_runtime.h>
#include <math.h>

#define NN      512
#define EE      16384
#define NDIM    64
#define HID     128
#define FFD     2048
#define VOCAB   50
#define SEQ     100

// quantum embedding constants: (cos(.05)-sin(.05)), cos(.1), sin(.1)
#define QA 0.94877109112428797f
#define QB 0.99500416527802582f
#define QC 0.099833416646828155f

// ---------------- stage A: quantum embedding + zero CSR counters ----------------

__global__ void k_prep(const float* __restrict__ x, float* __restrict__ qx,
                       int* __restrict__ cnt) {
    int i = blockIdx.x * 256 + threadIdx.x;
    if (i < NN * NDIM) {
        float v = x[i];
        qx[i] = QA * (QB * v + QC * tanhf(v));
    }
    if (i < NN) cnt[i] = 0;
}

// ------- stage B: hist | GCN1 mm | comb stage1 | FF-weight prefetch (independent) -------

struct BArgs {
    const int* ei; int* cnt;
    const float* qx; const float* g1w; float* pre1;
    const float* A[3]; const float* ab[3]; const float* Bm[3]; const float* bb[3];
    float* outM[3];
    const float* ab3; const float* B3; const float* bb3; float* out3;  // Msa0 bias row
    const float* fw1; const float* fw2; float* pf;                     // prefetch
};

__global__ void k_b(BArgs a) {
    int B = blockIdx.x, t = threadIdx.x;
    if (B < 64) {                              // hist: 16384 edges
        int e = B * 256 + t;
        atomicAdd(&a.cnt[a.ei[EE + e]], 1);
        return;
    }
    if (B < 320) {                             // GCN1 mm: pre1[512,128] = qx @ g1w
        int i = (B - 64) * 256 + t;
        int row = i >> 7, col = i & 127;
        const float* xr = a.qx + row * NDIM;
        float acc = 0.0f;
#pragma unroll 8
        for (int k = 0; k < NDIM; k++) acc = fmaf(xr[k], a.g1w[k * HID + col], acc);
        a.pre1[i] = acc;
        return;
    }
    if (B < 320 + 195) {                       // comb1: Msa1, Mca0, Mca1 (129x128 each)
        int q = B - 320;
        int jm = q / 65;
        int i = (q - jm * 65) * 256 + t;
        if (i >= 129 * HID) return;
        int rw = i >> 7, col = i & 127;
        const float* Bm = a.Bm[jm];
        float acc;
        if (rw < 128) {
            const float* ar = a.A[jm] + rw * HID;
            acc = 0.0f;
#pragma unroll 8
            for (int k = 0; k < HID; k++) acc = fmaf(ar[k], Bm[k * HID + col], acc);
        } else {
            acc = a.bb[jm][col];
#pragma unroll 8
            for (int k = 0; k < HID; k++) acc = fmaf(a.ab[jm][k], Bm[k * HID + col], acc);
        }
        a.outM[jm][i] = acc;
        return;
    }
    if (B == 515) {                            // Msa0 bias row (layer-0 self-attn const)
        if (t < HID) {
            float acc = a.bb3[t];
#pragma unroll 8
            for (int k = 0; k < HID; k++) acc = fmaf(a.ab3[k], a.B3[k * HID + t], acc);
            a.out3[t] = acc;
        }
        return;
    }
    // prefetch FF weights (4 MB) into L2/L3 while the front-end runs
    {
        int q = B - 516;                       // 0..511, 2048 floats each
        const float4* p = (const float4*)((q < 256) ? (a.fw1 + q * 2048)
                                                    : (a.fw2 + (q - 256) * 2048));
        float4 f0 = p[t];
        float4 f1 = p[t + 256];
        float s = (f0.x + f0.y + f0.z + f0.w) + (f1.x + f1.y + f1.z + f1.w);
#pragma unroll
        for (int o = 32; o > 0; o >>= 1) s += __shfl_down(s, o);
        if ((t & 63) == 0) a.pf[q * 4 + (t >> 6)] = s;   // keep loads live
    }
}

// ---------------- stage C: scan (block 0) | comb stage2 (fold fc into ca) ----------------

struct CArgs {
    const int* cnt; int* offs; int* cursor; float* dinv;
    const float* fcw; const float* fcb;
    const float* Mca0; const float* Mca1; float* Mfc0; float* Mfc1;
};

__global__ void k_c(CArgs a) {
    int B = blockIdx.x, t = threadIdx.x;
    if (B == 0) {                              // inclusive scan of 512 counts, 256 thr
        __shared__ int sh[512];
        int c0 = a.cnt[t], c1 = a.cnt[t + 256];
        sh[t] = c0; sh[t + 256] = c1;
        __syncthreads();
        for (int o = 1; o < 512; o <<= 1) {
            int x0 = (t >= o) ? sh[t - o] : 0;
            int x1 = (t + 256 >= o) ? sh[t + 256 - o] : 0;
            __syncthreads();
            sh[t] += x0; sh[t + 256] += x1;
            __syncthreads();
        }
        a.offs[t + 1] = sh[t];
        a.offs[t + 257] = sh[t + 256];
        if (t == 0) a.offs[0] = 0;
        a.cursor[t] = sh[t] - c0;
        a.cursor[t + 256] = sh[t + 256] - c1;
        a.dinv[t] = rsqrtf((float)c0 + 1.0f);
        a.dinv[t + 256] = rsqrtf((float)c1 + 1.0f);
        return;
    }
    int q = B - 1;
    int jm = q / 65;
    int i = (q - jm * 65) * 256 + t;
    if (i >= 129 * HID) return;
    int rw = i >> 7, col = i & 127;
    const float* M = jm ? a.Mca1 : a.Mca0;
    float* o = jm ? a.Mfc1 : a.Mfc0;
    float acc;
    if (rw < 128) {
        const float* ar = a.fcw + rw * HID;
        acc = 0.0f;
#pragma unroll 8
        for (int k = 0; k < HID; k++) acc = fmaf(ar[k], M[k * HID + col], acc);
    } else {
        acc = M[128 * HID + col];
#pragma unroll 8
        for (int k = 0; k < HID; k++) acc = fmaf(a.fcb[k], M[k * HID + col], acc);
    }
    o[i] = acc;
}

// ---------------- stage D: CSR scatter ----------------

__global__ void k_scatter(const int* __restrict__ ei, int* __restrict__ cursor,
                          int* __restrict__ csr) {
    int e = blockIdx.x * 256 + threadIdx.x;
    if (e < EE) {
        int d = ei[EE + e];
        int slot = atomicAdd(&cursor[d], 1);
        csr[slot] = ei[e];    // store src
    }
}

// ---------------- helpers ----------------

__device__ __forceinline__ float gather_row(const float* __restrict__ pre,
                                            const float* __restrict__ dinv,
                                            const int* __restrict__ offs,
                                            const int* __restrict__ csr,
                                            int row, int j) {
    float dd = dinv[row];
    float acc = pre[row * HID + j] * dd;
    int i = offs[row], e = offs[row + 1];
    for (; i + 3 < e; i += 4) {
        int s0 = csr[i], s1 = csr[i + 1], s2 = csr[i + 2], s3 = csr[i + 3];
        float a0 = pre[s0 * HID + j] * dinv[s0];
        float a1 = pre[s1 * HID + j] * dinv[s1];
        float a2 = pre[s2 * HID + j] * dinv[s2];
        float a3 = pre[s3 * HID + j] * dinv[s3];
        acc += (a0 + a1) + (a2 + a3);
    }
    for (; i < e; ++i) {
        int s = csr[i];
        acc += pre[s * HID + j] * dinv[s];
    }
    return acc * dd;
}

// layernorm for 2-rows-per-256-thread-block layout; sh = 8 floats scratch
__device__ __forceinline__ float rowln(float v, float w, float b, float* sh, int t) {
    int r = t >> 7;
    float s1 = v, s2 = v * v;
#pragma unroll
    for (int o = 32; o > 0; o >>= 1) {
        s1 += __shfl_down(s1, o);
        s2 += __shfl_down(s2, o);
    }
    int wv = (t >> 6) & 1;
    if ((t & 63) == 0) { sh[r * 4 + wv] = s1; sh[r * 4 + 2 + wv] = s2; }
    __syncthreads();
    float mean = (sh[r * 4] + sh[r * 4 + 1]) * (1.0f / HID);
    float m2   = (sh[r * 4 + 2] + sh[r * 4 + 3]) * (1.0f / HID);
    float rstd = rsqrtf(m2 - mean * mean + 1e-5f);
    float out = (v - mean) * rstd * w + b;
    __syncthreads();
    return out;
}

// ---------------- stage E: gather1 + bias/relu + GCN2 mm (row fused) ----------------

__global__ void k_gather_mm(const float* __restrict__ pre1, const float* __restrict__ dinv,
                            const int* __restrict__ offs, const int* __restrict__ csr,
                            const float* __restrict__ g1b, const float* __restrict__ g2w,
                            float* __restrict__ pre2) {
    __shared__ float sh_h[2][HID];
    int t = threadIdx.x, j = t & 127, r = t >> 7;
    int row = blockIdx.x * 2 + r;
    float g = gather_row(pre1, dinv, offs, csr, row, j);
    sh_h[r][j] = fmaxf(g + g1b[j], 0.0f);
    __syncthreads();
    float acc = 0.0f;
#pragma unroll 8
    for (int k = 0; k < HID; k++) acc = fmaf(sh_h[r][k], g2w[k * HID + j], acc);
    pre2[row * HID + j] = acc;
}

// ---------------- stage F: gather2 + ca0/ca1 + LN·LN -> t0 (row fused) ----------------

__global__ void k_row0(const float* __restrict__ pre2, const float* __restrict__ dinv,
                       const int* __restrict__ offs, const int* __restrict__ csr,
                       const float* __restrict__ g2b,
                       const float* __restrict__ Mfc0, const float* __restrict__ Mfc1,
                       const float* __restrict__ sa0bias,
                       const float* __restrict__ ln0w, const float* __restrict__ ln0b,
                       const float* __restrict__ ln1w, const float* __restrict__ ln1b,
                       float* __restrict__ ca1out, float* __restrict__ t0out) {
    __shared__ float sh_h[2][HID];
    __shared__ float shln[8];
    int t = threadIdx.x, j = t & 127, r = t >> 7;
    int row = blockIdx.x * 2 + r;
    float g = gather_row(pre2, dinv, offs, csr, row, j);
    sh_h[r][j] = fmaxf(g + g2b[j], 0.0f);
    __syncthreads();
    float a0 = Mfc0[128 * HID + j], a1 = Mfc1[128 * HID + j];
#pragma unroll 4
    for (int k = 0; k < HID; k++) {
        float hk = sh_h[r][k];
        a0 = fmaf(hk, Mfc0[k * HID + j], a0);
        a1 = fmaf(hk, Mfc1[k * HID + j], a1);
    }
    ca1out[row * HID + j] = a1;
    float v = rowln(sa0bias[j], ln0w[j], ln0b[j], shln, t);   // LN(tgt0 + sa0) row-const
    v = rowln(v + a0, ln1w[j], ln1b[j], shln, t);
    t0out[row * HID + j] = v;
}

// ---------------- stages G/I: fused FF (128->2048->128), split-K partials ----------------
// grid 512 x 512thr: kc = blk&7 owns mid cols [kc*256,+256); rg = blk>>3 owns rows [rg*8,+8)
// phase1: t -> (rowgrp = t>>6, col4 = (t&63)*4); phase2: t -> (half = t>>8,
// rowgrp = (t>>5)&7, col4 = (t&31)*4), halves reduced through LDS.

__global__ __launch_bounds__(512, 4)
void k_fff(const float* __restrict__ tin, const float* __restrict__ W1,
           const float* __restrict__ b1, const float* __restrict__ W2,
           float* __restrict__ part) {
    __shared__ float sh_t[8][HID];      // 4 KB (reused as half-reduction scratch)
    __shared__ float sh_m[8][256];      // 8 KB
    int t = threadIdx.x;
    int kc = blockIdx.x & 7, rg = blockIdx.x >> 3;
    int row0 = rg * 8, c0 = kc * 256;

    if (t < 256) {                      // load 8x128 input rows as float4
        const float4* tp = (const float4*)(tin + row0 * HID);
        float4 v = tp[t];
        *(float4*)&sh_t[t >> 5][(t & 31) * 4] = v;
    }
    __syncthreads();

    // phase 1: mid[8][256] = relu(t @ W1 + b1) on this column slice
    {
        int rowg = t >> 6;
        int col4 = (t & 63) * 4;
        float4 bias = *(const float4*)&b1[c0 + col4];
        float a0 = bias.x, a1 = bias.y, a2 = bias.z, a3 = bias.w;
        const float* w1p = W1 + c0 + col4;
#pragma unroll 8
        for (int k = 0; k < HID; k++) {
            float4 w = *(const float4*)&w1p[k * FFD];
            float s = sh_t[rowg][k];
            a0 = fmaf(s, w.x, a0); a1 = fmaf(s, w.y, a1);
            a2 = fmaf(s, w.z, a2); a3 = fmaf(s, w.w, a3);
        }
        float4 m;
        m.x = fmaxf(a0, 0.f); m.y = fmaxf(a1, 0.f);
        m.z = fmaxf(a2, 0.f); m.w = fmaxf(a3, 0.f);
        *(float4*)&sh_m[rowg][col4] = m;
    }
    __syncthreads();

    // phase 2: partial out[8][128] = mid @ W2 slice; K split across t>>8 halves
    {
        int col4 = (t & 31) * 4;
        int rowg = (t >> 5) & 7;
        int half = t >> 8;
        int kb = half * 128;
        float a0 = 0.f, a1 = 0.f, a2 = 0.f, a3 = 0.f;
        const float* w2p = W2 + (c0 + kb) * HID + col4;
        const float* mp = &sh_m[rowg][kb];
#pragma unroll 8
        for (int kk = 0; kk < 128; kk++) {
            float4 w = *(const float4*)&w2p[kk * HID];
            float m = mp[kk];
            a0 = fmaf(m, w.x, a0); a1 = fmaf(m, w.y, a1);
            a2 = fmaf(m, w.z, a2); a3 = fmaf(m, w.w, a3);
        }
        __syncthreads();
        float* shred = &sh_t[0][0];      // 1024 floats
        if (half) {
            float4 r; r.x = a0; r.y = a1; r.z = a2; r.w = a3;
            *(float4*)&shred[(t - 256) * 4] = r;
        }
        __syncthreads();
        if (!half) {
            float4 o = *(float4*)&shred[t * 4];
            o.x += a0; o.y += a1; o.z += a2; o.w += a3;
            *(float4*)&part[kc * (NN * HID) + (row0 + rowg) * HID + col4] = o;
        }
    }
}

// ---------------- stage H: ff2 reduce + LN + sa1 + LN + LN -> t2 (row fused) ----------------

__global__ void k_row1(const float* __restrict__ part, const float* __restrict__ fb2,
                       const float* __restrict__ t0, const float* __restrict__ Msa1,
                       const float* __restrict__ ca1,
                       const float* __restrict__ ln2w, const float* __restrict__ ln2b,
                       const float* __restrict__ ln3w, const float* __restrict__ ln3b,
                       const float* __restrict__ ln4w, const float* __restrict__ ln4b,
                       float* __restrict__ t2out) {
    __shared__ float sh_t1[2][HID];
    __shared__ float shln[8];
    int t = threadIdx.x, j = t & 127, r = t >> 7;
    int row = blockIdx.x * 2 + r;
    float v = fb2[j] + t0[row * HID + j];
#pragma unroll
    for (int s = 0; s < 8; s++) v += part[s * (NN * HID) + row * HID + j];
    v = rowln(v, ln2w[j], ln2b[j], shln, t);          // t1
    sh_t1[r][j] = v;
    __syncthreads();
    float s1 = Msa1[128 * HID + j];
#pragma unroll 8
    for (int k = 0; k < HID; k++) s1 = fmaf(sh_t1[r][k], Msa1[k * HID + j], s1);
    float u = rowln(v + s1, ln3w[j], ln3b[j], shln, t);
    u = rowln(u + ca1[row * HID + j], ln4w[j], ln4b[j], shln, t);
    t2out[row * HID + j] = u;
}

// ---------------- stage J: ff2 reduce + LN + logits + broadcast ----------------

__global__ void k_rowout(const float* __restrict__ part, const float* __restrict__ fb2,
                         const float* __restrict__ t2,
                         const float* __restrict__ ln5w, const float* __restrict__ ln5b,
                         const float* __restrict__ ow, const float* __restrict__ ob,
                         float* __restrict__ out) {
    __shared__ float sh3[2][HID];
    __shared__ float shln[8];
    __shared__ float sh_lg[100];
    int t = threadIdx.x, j = t & 127, r = t >> 7;
    int row = blockIdx.x * 2 + r;
    float v = fb2[j] + t2[row * HID + j];
#pragma unroll
    for (int s = 0; s < 8; s++) v += part[s * (NN * HID) + row * HID + j];
    v = rowln(v, ln5w[j], ln5b[j], shln, t);
    sh3[r][j] = v;
    __syncthreads();
    if (j < VOCAB) {
        float acc = ob[j];
#pragma unroll 8
        for (int k = 0; k < HID; k++) acc = fmaf(sh3[r][k], ow[k * VOCAB + j], acc);
        sh_lg[r * VOCAB + j] = acc;
    }
    __syncthreads();
    int base = blockIdx.x * (2 * VOCAB);
    for (int idx = t; idx < SEQ * 2 * VOCAB; idx += 256) {
        int s = idx / (2 * VOCAB), p = idx - s * (2 * VOCAB);
        out[s * (NN * VOCAB) + base + p] = sh_lg[p];
    }
}

// ---------------- launch ----------------

extern "C" void kernel_launch(void* const* d_in, const int* in_sizes, int n_in,
                              void* d_out, int out_size, void* d_ws, size_t ws_size,
                              hipStream_t stream) {
    (void)in_sizes; (void)n_in; (void)out_size; (void)ws_size;
    const float* x   = (const float*)d_in[0];
    const int*   ei  = (const int*)d_in[1];
    const float* g1w = (const float*)d_in[2];
    const float* g1b = (const float*)d_in[3];
    const float* g2w = (const float*)d_in[4];
    const float* g2b = (const float*)d_in[5];
    const float* fcw = (const float*)d_in[6];
    const float* fcb = (const float*)d_in[7];
    const float* saw = (const float*)d_in[8];
    const float* sab = (const float*)d_in[9];
    const float* caw = (const float*)d_in[10];
    const float* cab = (const float*)d_in[11];
    const float* lnw = (const float*)d_in[12];
    const float* lnb = (const float*)d_in[13];
    const float* fw1 = (const float*)d_in[14];
    const float* fb1 = (const float*)d_in[15];
    const float* fw2 = (const float*)d_in[16];
    const float* fb2 = (const float*)d_in[17];
    const float* ow  = (const float*)d_in[18];
    const float* ob  = (const float*)d_in[19];
    float* out = (float*)d_out;

    // workspace layout (float offsets); total ~988K floats = 3.95 MB
    float* ws      = (float*)d_ws;
    float* qx      = ws;                 // 32768
    float* pre1    = ws + 32768;         // 65536
    float* pre2    = ws + 98304;         // 65536
    float* t0      = ws + 163840;        // 65536
    float* t2      = ws + 229376;        // 65536
    float* ca1     = ws + 294912;        // 65536
    float* Msa1    = ws + 360448;        // 16512
    float* Mca0    = ws + 376960;        // 16512
    float* Mca1    = ws + 393472;        // 16512
    float* Mfc0    = ws + 409984;        // 16512
    float* Mfc1    = ws + 426496;        // 16512
    float* sa0bias = ws + 443008;        // 128
    float* dinv    = ws + 443136;        // 512
    int*   cnt     = (int*)(ws + 443648);  // 512
    int*   offs    = cnt + 512;            // 513 (+pad)
    int*   cursor  = offs + 516;           // 512
    int*   csr     = cursor + 512;         // 16384
    float* part    = ws + 461824;        // 8*65536 = 524288
    float* pf      = ws + 986112;        // 2048 (prefetch sink)

    // A
    k_prep<<<128, 256, 0, stream>>>(x, qx, cnt);

    // B: hist | mm1 | comb1(Msa1, Mca0, Mca1, sa0bias) | FF-weight prefetch
    {
        BArgs a;
        a.ei = ei; a.cnt = cnt; a.qx = qx; a.g1w = g1w; a.pre1 = pre1;
        a.A[0]  = saw + (4 + 2) * HID * HID;  a.ab[0] = sab + (4 + 2) * HID;
        a.Bm[0] = saw + (4 + 3) * HID * HID;  a.bb[0] = sab + (4 + 3) * HID;
        a.outM[0] = Msa1;
        a.A[1]  = caw + 2 * HID * HID;        a.ab[1] = cab + 2 * HID;
        a.Bm[1] = caw + 3 * HID * HID;        a.bb[1] = cab + 3 * HID;
        a.outM[1] = Mca0;
        a.A[2]  = caw + (4 + 2) * HID * HID;  a.ab[2] = cab + (4 + 2) * HID;
        a.Bm[2] = caw + (4 + 3) * HID * HID;  a.bb[2] = cab + (4 + 3) * HID;
        a.outM[2] = Mca1;
        a.ab3 = sab + 2 * HID;  a.B3 = saw + 3 * HID * HID;  a.bb3 = sab + 3 * HID;
        a.out3 = sa0bias;
        a.fw1 = fw1; a.fw2 = fw2; a.pf = pf;
        k_b<<<1028, 256, 0, stream>>>(a);
    }

    // C: scan | comb2 (fold fc into Mca -> Mfc)
    {
        CArgs a;
        a.cnt = cnt; a.offs = offs; a.cursor = cursor; a.dinv = dinv;
        a.fcw = fcw; a.fcb = fcb;
        a.Mca0 = Mca0; a.Mca1 = Mca1; a.Mfc0 = Mfc0; a.Mfc1 = Mfc1;
        k_c<<<131, 256, 0, stream>>>(a);
    }

    // D
    k_scatter<<<64, 256, 0, stream>>>(ei, cursor, csr);

    // E: gather1 + relu + mm2
    k_gather_mm<<<256, 256, 0, stream>>>(pre1, dinv, offs, csr, g1b, g2w, pre2);

    // F: gather2 + ca0/ca1 + LN.LN -> t0
    k_row0<<<256, 256, 0, stream>>>(pre2, dinv, offs, csr, g2b, Mfc0, Mfc1, sa0bias,
                                    lnw + 0 * HID, lnb + 0 * HID,
                                    lnw + 1 * HID, lnb + 1 * HID, ca1, t0);

    // G: FF layer 0
    k_fff<<<512, 512, 0, stream>>>(t0, fw1, fb1, fw2, part);

    // H: reduce + LN2 + sa1 + LN3 + LN4 -> t2
    k_row1<<<256, 256, 0, stream>>>(part, fb2, t0, Msa1, ca1,
                                    lnw + 2 * HID, lnb + 2 * HID,
                                    lnw + 3 * HID, lnb + 3 * HID,
                                    lnw + 4 * HID, lnb + 4 * HID, t2);

    // I: FF layer 1
    k_fff<<<512, 512, 0, stream>>>(t2, fw1 + HID * FFD, fb1 + FFD, fw2 + FFD * HID, part);

    // J: reduce + LN5 + logits + broadcast
    k_rowout<<<256, 256, 0, stream>>>(part, fb2 + HID, t2,
                                      lnw + 5 * HID, lnb + 5 * HID, ow, ob, out);
}

// Round 5
// 120.182 us; speedup vs baseline: 1.1235x; 1.1235x over previous
//
#include <hip/hip_runtime.h>
#include <math.h>

#define NN      512
#define EE      16384
#define NDIM    64
#define HID     128
#define FFD     2048
#define VOCAB   50
#define SEQ     100

// quantum embedding constants: (cos(.05)-sin(.05)), cos(.1), sin(.1)
#define QA 0.94877109112428797f
#define QB 0.99500416527802582f
#define QC 0.099833416646828155f

// ------- stage B: hist | (qx+GCN1 mm) | comb stage1 | sa0 bias row (independent) -------

struct BArgs {
    const int* ei; int* cnt;
    const float* x; const float* g1w; float* pre1;
    const float* A[3]; const float* ab[3]; const float* Bm[3]; const float* bb[3];
    float* outM[3];
    const float* ab3; const float* B3; const float* bb3; float* out3;  // Msa0 bias row
};

__global__ void k_b(BArgs a) {
    int B = blockIdx.x, t = threadIdx.x;
    if (B < 64) {                              // hist: 16384 edges
        int e = B * 256 + t;
        atomicAdd(&a.cnt[a.ei[EE + e]], 1);
        return;
    }
    if (B < 320) {                             // GCN1 mm with inline quantum embedding
        __shared__ float qxs[2][NDIM];
        int q = B - 64;                        // 2 rows per block
        int row0 = q * 2;
        if (t < 2 * NDIM) {
            float v = a.x[row0 * NDIM + t];
            qxs[t >> 6][t & 63] = QA * (QB * v + QC * tanhf(v));
        }
        __syncthreads();
        int r = t >> 7, col = t & 127;
        float acc = 0.0f;
#pragma unroll 8
        for (int k = 0; k < NDIM; k++) acc = fmaf(qxs[r][k], a.g1w[k * HID + col], acc);
        a.pre1[(row0 + r) * HID + col] = acc;
        return;
    }
    if (B < 320 + 195) {                       // comb1: Msa1, Mca0, Mca1 (129x128 each)
        int q = B - 320;
        int jm = q / 65;
        int i = (q - jm * 65) * 256 + t;
        if (i >= 129 * HID) return;
        int rw = i >> 7, col = i & 127;
        const float* Bm = a.Bm[jm];
        float acc;
        if (rw < 128) {
            const float* ar = a.A[jm] + rw * HID;
            acc = 0.0f;
#pragma unroll 8
            for (int k = 0; k < HID; k++) acc = fmaf(ar[k], Bm[k * HID + col], acc);
        } else {
            acc = a.bb[jm][col];
#pragma unroll 8
            for (int k = 0; k < HID; k++) acc = fmaf(a.ab[jm][k], Bm[k * HID + col], acc);
        }
        a.outM[jm][i] = acc;
        return;
    }
    // last block: Msa0 bias row (layer-0 self-attn of tgt=0 is a constant row)
    if (t < HID) {
        float acc = a.bb3[t];
#pragma unroll 8
        for (int k = 0; k < HID; k++) acc = fmaf(a.ab3[k], a.B3[k * HID + t], acc);
        a.out3[t] = acc;
    }
}

// ---------------- stage C: scan (block 0) | comb stage2 (fold fc into ca) ----------------

struct CArgs {
    const int* cnt; int* offs; int* cursor; float* dinv;
    const float* fcw; const float* fcb;
    const float* Mca0; const float* Mca1; float* Mfc0; float* Mfc1;
};

__global__ void k_c(CArgs a) {
    int B = blockIdx.x, t = threadIdx.x;
    if (B == 0) {                              // inclusive scan of 512 counts, 256 thr
        __shared__ int sh[512];
        int c0 = a.cnt[t], c1 = a.cnt[t + 256];
        sh[t] = c0; sh[t + 256] = c1;
        __syncthreads();
        for (int o = 1; o < 512; o <<= 1) {
            int x0 = (t >= o) ? sh[t - o] : 0;
            int x1 = (t + 256 >= o) ? sh[t + 256 - o] : 0;
            __syncthreads();
            sh[t] += x0; sh[t + 256] += x1;
            __syncthreads();
        }
        a.offs[t + 1] = sh[t];
        a.offs[t + 257] = sh[t + 256];
        if (t == 0) a.offs[0] = 0;
        a.cursor[t] = sh[t] - c0;
        a.cursor[t + 256] = sh[t + 256] - c1;
        a.dinv[t] = rsqrtf((float)c0 + 1.0f);
        a.dinv[t + 256] = rsqrtf((float)c1 + 1.0f);
        return;
    }
    int q = B - 1;
    int jm = q / 65;
    int i = (q - jm * 65) * 256 + t;
    if (i >= 129 * HID) return;
    int rw = i >> 7, col = i & 127;
    const float* M = jm ? a.Mca1 : a.Mca0;
    float* o = jm ? a.Mfc1 : a.Mfc0;
    float acc;
    if (rw < 128) {
        const float* ar = a.fcw + rw * HID;
        acc = 0.0f;
#pragma unroll 8
        for (int k = 0; k < HID; k++) acc = fmaf(ar[k], M[k * HID + col], acc);
    } else {
        acc = M[128 * HID + col];
#pragma unroll 8
        for (int k = 0; k < HID; k++) acc = fmaf(a.fcb[k], M[k * HID + col], acc);
    }
    o[i] = acc;
}

// ---------------- stage D: CSR scatter ----------------

__global__ void k_scatter(const int* __restrict__ ei, int* __restrict__ cursor,
                          int* __restrict__ csr) {
    int e = blockIdx.x * 256 + threadIdx.x;
    if (e < EE) {
        int d = ei[EE + e];
        int slot = atomicAdd(&cursor[d], 1);
        csr[slot] = ei[e];    // store src
    }
}

// ---------------- helpers ----------------

__device__ __forceinline__ float gather_row(const float* __restrict__ pre,
                                            const float* __restrict__ dinv,
                                            const int* __restrict__ offs,
                                            const int* __restrict__ csr,
                                            int row, int j) {
    float dd = dinv[row];
    float acc = pre[row * HID + j] * dd;
    int i = offs[row], e = offs[row + 1];
    for (; i + 3 < e; i += 4) {
        int s0 = csr[i], s1 = csr[i + 1], s2 = csr[i + 2], s3 = csr[i + 3];
        float a0 = pre[s0 * HID + j] * dinv[s0];
        float a1 = pre[s1 * HID + j] * dinv[s1];
        float a2 = pre[s2 * HID + j] * dinv[s2];
        float a3 = pre[s3 * HID + j] * dinv[s3];
        acc += (a0 + a1) + (a2 + a3);
    }
    for (; i < e; ++i) {
        int s = csr[i];
        acc += pre[s * HID + j] * dinv[s];
    }
    return acc * dd;
}

// layernorm for 2-rows-per-256-thread-block layout; sh = 8 floats scratch
__device__ __forceinline__ float rowln(float v, float w, float b, float* sh, int t) {
    int r = t >> 7;
    float s1 = v, s2 = v * v;
#pragma unroll
    for (int o = 32; o > 0; o >>= 1) {
        s1 += __shfl_down(s1, o);
        s2 += __shfl_down(s2, o);
    }
    int wv = (t >> 6) & 1;
    if ((t & 63) == 0) { sh[r * 4 + wv] = s1; sh[r * 4 + 2 + wv] = s2; }
    __syncthreads();
    float mean = (sh[r * 4] + sh[r * 4 + 1]) * (1.0f / HID);
    float m2   = (sh[r * 4 + 2] + sh[r * 4 + 3]) * (1.0f / HID);
    float rstd = rsqrtf(m2 - mean * mean + 1e-5f);
    float out = (v - mean) * rstd * w + b;
    __syncthreads();
    return out;
}

// ---------------- stage E: gather1 + bias/relu + GCN2 mm (row fused) ----------------

__global__ void k_gather_mm(const float* __restrict__ pre1, const float* __restrict__ dinv,
                            const int* __restrict__ offs, const int* __restrict__ csr,
                            const float* __restrict__ g1b, const float* __restrict__ g2w,
                            float* __restrict__ pre2) {
    __shared__ float sh_h[2][HID];
    int t = threadIdx.x, j = t & 127, r = t >> 7;
    int row = blockIdx.x * 2 + r;
    float g = gather_row(pre1, dinv, offs, csr, row, j);
    sh_h[r][j] = fmaxf(g + g1b[j], 0.0f);
    __syncthreads();
    float acc = 0.0f;
#pragma unroll 8
    for (int k = 0; k < HID; k++) acc = fmaf(sh_h[r][k], g2w[k * HID + j], acc);
    pre2[row * HID + j] = acc;
}

// ---------------- stage F: gather2 + ca0/ca1 + LN·LN -> t0 (row fused) ----------------

__global__ void k_row0(const float* __restrict__ pre2, const float* __restrict__ dinv,
                       const int* __restrict__ offs, const int* __restrict__ csr,
                       const float* __restrict__ g2b,
                       const float* __restrict__ Mfc0, const float* __restrict__ Mfc1,
                       const float* __restrict__ sa0bias,
                       const float* __restrict__ ln0w, const float* __restrict__ ln0b,
                       const float* __restrict__ ln1w, const float* __restrict__ ln1b,
                       float* __restrict__ ca1out, float* __restrict__ t0out) {
    __shared__ float sh_h[2][HID];
    __shared__ float shln[8];
    int t = threadIdx.x, j = t & 127, r = t >> 7;
    int row = blockIdx.x * 2 + r;
    float g = gather_row(pre2, dinv, offs, csr, row, j);
    sh_h[r][j] = fmaxf(g + g2b[j], 0.0f);
    __syncthreads();
    float a0 = Mfc0[128 * HID + j], a1 = Mfc1[128 * HID + j];
#pragma unroll 4
    for (int k = 0; k < HID; k++) {
        float hk = sh_h[r][k];
        a0 = fmaf(hk, Mfc0[k * HID + j], a0);
        a1 = fmaf(hk, Mfc1[k * HID + j], a1);
    }
    ca1out[row * HID + j] = a1;
    float v = rowln(sa0bias[j], ln0w[j], ln0b[j], shln, t);   // LN(tgt0 + sa0) row-const
    v = rowln(v + a0, ln1w[j], ln1b[j], shln, t);
    t0out[row * HID + j] = v;
}

// ---------------- stages G/I: fused FF (128->2048->128), split-K partials ----------------
// grid 256 x 512thr: kc = blk&7 owns mid cols [kc*256,+256); rg = blk>>3 owns rows [rg*16,+16)
// phase1: thread owns 2 rows x 4 cols (each W1 float4 feeds 8 FMAs).
// phase2: thread owns 1 row x 4 cols over full 256-K slice.

__global__ __launch_bounds__(512)
void k_fff(const float* __restrict__ tin, const float* __restrict__ W1,
           const float* __restrict__ b1, const float* __restrict__ W2,
           float* __restrict__ part) {
    __shared__ float sh_t[16][HID];      // 8 KB
    __shared__ float sh_m[16][256];      // 16 KB
    int t = threadIdx.x;
    int kc = blockIdx.x & 7, rg = blockIdx.x >> 3;   // rg 0..31
    int row0 = rg * 16, c0 = kc * 256;

    {   // load 16x128 input rows = 512 float4, one per thread
        const float4* tp = (const float4*)(tin + row0 * HID);
        float4 v = tp[t];
        *(float4*)&sh_t[t >> 5][(t & 31) * 4] = v;
    }
    __syncthreads();

    // phase 1: mid[16][256] = relu(t @ W1 + b1) on this column slice
    {
        int rg2  = t >> 6;            // 0..7 -> rows 2*rg2, 2*rg2+1
        int col4 = (t & 63) * 4;      // 0..252
        float4 bias = *(const float4*)&b1[c0 + col4];
        float a00 = bias.x, a01 = bias.y, a02 = bias.z, a03 = bias.w;
        float a10 = bias.x, a11 = bias.y, a12 = bias.z, a13 = bias.w;
        const float* w1p = W1 + c0 + col4;
        const float* x0 = sh_t[2 * rg2];
        const float* x1 = sh_t[2 * rg2 + 1];
#pragma unroll 8
        for (int k = 0; k < HID; k++) {
            float4 w = *(const float4*)&w1p[k * FFD];
            float s0 = x0[k], s1 = x1[k];
            a00 = fmaf(s0, w.x, a00); a01 = fmaf(s0, w.y, a01);
            a02 = fmaf(s0, w.z, a02); a03 = fmaf(s0, w.w, a03);
            a10 = fmaf(s1, w.x, a10); a11 = fmaf(s1, w.y, a11);
            a12 = fmaf(s1, w.z, a12); a13 = fmaf(s1, w.w, a13);
        }
        float4 m0, m1;
        m0.x = fmaxf(a00, 0.f); m0.y = fmaxf(a01, 0.f);
        m0.z = fmaxf(a02, 0.f); m0.w = fmaxf(a03, 0.f);
        m1.x = fmaxf(a10, 0.f); m1.y = fmaxf(a11, 0.f);
        m1.z = fmaxf(a12, 0.f); m1.w = fmaxf(a13, 0.f);
        *(float4*)&sh_m[2 * rg2][col4]     = m0;
        *(float4*)&sh_m[2 * rg2 + 1][col4] = m1;
    }
    __syncthreads();

    // phase 2: partial out[16][128] = mid @ W2 slice
    {
        int rowg = t >> 5;            // 0..15
        int col4 = (t & 31) * 4;      // 0..124
        float a0 = 0.f, a1 = 0.f, a2 = 0.f, a3 = 0.f;
        const float* w2p = W2 + c0 * HID + col4;
        const float* mp = sh_m[rowg];
#pragma unroll 8
        for (int kk = 0; kk < 256; kk++) {
            float4 w = *(const float4*)&w2p[kk * HID];
            float m = mp[kk];
            a0 = fmaf(m, w.x, a0); a1 = fmaf(m, w.y, a1);
            a2 = fmaf(m, w.z, a2); a3 = fmaf(m, w.w, a3);
        }
        float4 o; o.x = a0; o.y = a1; o.z = a2; o.w = a3;
        *(float4*)&part[kc * (NN * HID) + (row0 + rowg) * HID + col4] = o;
    }
}

// ---------------- stage H: ff2 reduce + LN + sa1 + LN + LN -> t2 (row fused) ----------------

__global__ void k_row1(const float* __restrict__ part, const float* __restrict__ fb2,
                       const float* __restrict__ t0, const float* __restrict__ Msa1,
                       const float* __restrict__ ca1,
                       const float* __restrict__ ln2w, const float* __restrict__ ln2b,
                       const float* __restrict__ ln3w, const float* __restrict__ ln3b,
                       const float* __restrict__ ln4w, const float* __restrict__ ln4b,
                       float* __restrict__ t2out) {
    __shared__ float sh_t1[2][HID];
    __shared__ float shln[8];
    int t = threadIdx.x, j = t & 127, r = t >> 7;
    int row = blockIdx.x * 2 + r;
    float v = fb2[j] + t0[row * HID + j];
#pragma unroll
    for (int s = 0; s < 8; s++) v += part[s * (NN * HID) + row * HID + j];
    v = rowln(v, ln2w[j], ln2b[j], shln, t);          // t1
    sh_t1[r][j] = v;
    __syncthreads();
    float s1 = Msa1[128 * HID + j];
#pragma unroll 8
    for (int k = 0; k < HID; k++) s1 = fmaf(sh_t1[r][k], Msa1[k * HID + j], s1);
    float u = rowln(v + s1, ln3w[j], ln3b[j], shln, t);
    u = rowln(u + ca1[row * HID + j], ln4w[j], ln4b[j], shln, t);
    t2out[row * HID + j] = u;
}

// ---------------- stage J: ff2 reduce + LN + logits + broadcast ----------------

__global__ void k_rowout(const float* __restrict__ part, const float* __restrict__ fb2,
                         const float* __restrict__ t2,
                         const float* __restrict__ ln5w, const float* __restrict__ ln5b,
                         const float* __restrict__ ow, const float* __restrict__ ob,
                         float* __restrict__ out) {
    __shared__ float sh3[2][HID];
    __shared__ float shln[8];
    __shared__ __align__(16) float sh_lg[100];
    int t = threadIdx.x, j = t & 127, r = t >> 7;
    int row = blockIdx.x * 2 + r;
    float v = fb2[j] + t2[row * HID + j];
#pragma unroll
    for (int s = 0; s < 8; s++) v += part[s * (NN * HID) + row * HID + j];
    v = rowln(v, ln5w[j], ln5b[j], shln, t);
    sh3[r][j] = v;
    __syncthreads();
    if (j < VOCAB) {
        float acc = ob[j];
#pragma unroll 8
        for (int k = 0; k < HID; k++) acc = fmaf(sh3[r][k], ow[k * VOCAB + j], acc);
        sh_lg[r * VOCAB + j] = acc;
    }
    __syncthreads();
    int base = blockIdx.x * (2 * VOCAB);     // multiple of 100 -> 16B aligned
    for (int idx = t; idx < SEQ * 25; idx += 256) {
        int s = idx / 25, p4 = (idx - s * 25) * 4;
        *(float4*)&out[s * (NN * VOCAB) + base + p4] = *(const float4*)&sh_lg[p4];
    }
}

// ---------------- launch ----------------

extern "C" void kernel_launch(void* const* d_in, const int* in_sizes, int n_in,
                              void* d_out, int out_size, void* d_ws, size_t ws_size,
                              hipStream_t stream) {
    (void)in_sizes; (void)n_in; (void)out_size; (void)ws_size;
    const float* x   = (const float*)d_in[0];
    const int*   ei  = (const int*)d_in[1];
    const float* g1w = (const float*)d_in[2];
    const float* g1b = (const float*)d_in[3];
    const float* g2w = (const float*)d_in[4];
    const float* g2b = (const float*)d_in[5];
    const float* fcw = (const float*)d_in[6];
    const float* fcb = (const float*)d_in[7];
    const float* saw = (const float*)d_in[8];
    const float* sab = (const float*)d_in[9];
    const float* caw = (const float*)d_in[10];
    const float* cab = (const float*)d_in[11];
    const float* lnw = (const float*)d_in[12];
    const float* lnb = (const float*)d_in[13];
    const float* fw1 = (const float*)d_in[14];
    const float* fb1 = (const float*)d_in[15];
    const float* fw2 = (const float*)d_in[16];
    const float* fb2 = (const float*)d_in[17];
    const float* ow  = (const float*)d_in[18];
    const float* ob  = (const float*)d_in[19];
    float* out = (float*)d_out;

    // workspace layout (float offsets); total ~986K floats = 3.95 MB
    float* ws      = (float*)d_ws;
    float* pre1    = ws;                 // 65536
    float* pre2    = ws + 65536;         // 65536
    float* t0      = ws + 131072;        // 65536
    float* t2      = ws + 196608;        // 65536
    float* ca1     = ws + 262144;        // 65536
    float* Msa1    = ws + 327680;        // 16512
    float* Mca0    = ws + 344192;        // 16512
    float* Mca1    = ws + 360704;        // 16512
    float* Mfc0    = ws + 377216;        // 16512
    float* Mfc1    = ws + 393728;        // 16512
    float* sa0bias = ws + 410240;        // 128
    float* dinv    = ws + 410368;        // 512
    int*   cnt     = (int*)(ws + 410880);  // 512
    int*   offs    = cnt + 512;            // 513 (+pad)
    int*   cursor  = offs + 516;           // 512
    int*   csr     = cursor + 512;         // 16384
    float* part    = ws + 429056;        // 8*65536 = 524288

    // zero CSR counters (graph-capturable async memset)
    hipMemsetAsync(cnt, 0, 512 * sizeof(int), stream);

    // B: hist | qx+mm1 | comb1(Msa1, Mca0, Mca1) | sa0bias
    {
        BArgs a;
        a.ei = ei; a.cnt = cnt; a.x = x; a.g1w = g1w; a.pre1 = pre1;
        a.A[0]  = saw + (4 + 2) * HID * HID;  a.ab[0] = sab + (4 + 2) * HID;
        a.Bm[0] = saw + (4 + 3) * HID * HID;  a.bb[0] = sab + (4 + 3) * HID;
        a.outM[0] = Msa1;
        a.A[1]  = caw + 2 * HID * HID;        a.ab[1] = cab + 2 * HID;
        a.Bm[1] = caw + 3 * HID * HID;        a.bb[1] = cab + 3 * HID;
        a.outM[1] = Mca0;
        a.A[2]  = caw + (4 + 2) * HID * HID;  a.ab[2] = cab + (4 + 2) * HID;
        a.Bm[2] = caw + (4 + 3) * HID * HID;  a.bb[2] = cab + (4 + 3) * HID;
        a.outM[2] = Mca1;
        a.ab3 = sab + 2 * HID;  a.B3 = saw + 3 * HID * HID;  a.bb3 = sab + 3 * HID;
        a.out3 = sa0bias;
        k_b<<<516, 256, 0, stream>>>(a);
    }

    // C: scan | comb2 (fold fc into Mca -> Mfc)
    {
        CArgs a;
        a.cnt = cnt; a.offs = offs; a.cursor = cursor; a.dinv = dinv;
        a.fcw = fcw; a.fcb = fcb;
        a.Mca0 = Mca0; a.Mca1 = Mca1; a.Mfc0 = Mfc0; a.Mfc1 = Mfc1;
        k_c<<<131, 256, 0, stream>>>(a);
    }

    // D
    k_scatter<<<64, 256, 0, stream>>>(ei, cursor, csr);

    // E: gather1 + relu + mm2
    k_gather_mm<<<256, 256, 0, stream>>>(pre1, dinv, offs, csr, g1b, g2w, pre2);

    // F: gather2 + ca0/ca1 + LN.LN -> t0
    k_row0<<<256, 256, 0, stream>>>(pre2, dinv, offs, csr, g2b, Mfc0, Mfc1, sa0bias,
                                    lnw + 0 * HID, lnb + 0 * HID,
                                    lnw + 1 * HID, lnb + 1 * HID, ca1, t0);

    // G: FF layer 0
    k_fff<<<256, 512, 0, stream>>>(t0, fw1, fb1, fw2, part);

    // H: reduce + LN2 + sa1 + LN3 + LN4 -> t2
    k_row1<<<256, 256, 0, stream>>>(part, fb2, t0, Msa1, ca1,
                                    lnw + 2 * HID, lnb + 2 * HID,
                                    lnw + 3 * HID, lnb + 3 * HID,
                                    lnw + 4 * HID, lnb + 4 * HID, t2);

    // I: FF layer 1
    k_fff<<<256, 512, 0, stream>>>(t2, fw1 + HID * FFD, fb1 + FFD, fw2 + FFD * HID, part);

    // J: reduce + LN5 + logits + broadcast
    k_rowout<<<256, 256, 0, stream>>>(part, fb2 + HID, t2,
                                      lnw + 5 * HID, lnb + 5 * HID, ow, ob, out);
}